// Round 4
// baseline (12469.002 us; speedup 1.0000x reference)
//
#include <hip/hip_runtime.h>
#include <stdint.h>

// Problem constants
#define SLEN 512
#define NBATCH 64
#define EMB 1024
#define HID 1024
#define G4 4096            // 4*H
#define D2H 2048           // 2*H
#define CT 64              // chunk timesteps
#define NC (SLEN/CT)       // 8 chunks
#define CROWS (CT*NBATCH)  // 4096 rows per chunk per dir
#define HSLOT (NBATCH*D2H) // elems per h timestep slot

typedef __bf16 bf16x8 __attribute__((ext_vector_type(8)));
typedef float  f32x4  __attribute__((ext_vector_type(4)));

__device__ __forceinline__ ushort f2bf(float x){
  union { float f; uint32_t u; } v; v.f = x;
  uint32_t r = (v.u + 0x7fffu + ((v.u >> 16) & 1u)) >> 16;   // RNE
  return (ushort)r;
}
__device__ __forceinline__ float bf2f(uint32_t u){
  union { uint32_t u; float f; } v; v.u = u << 16;
  return v.f;
}
__device__ __forceinline__ float sigm(float x){ return 1.f / (1.f + __expf(-x)); }
__device__ __forceinline__ float tanh_s(float x){ return 2.f / (1.f + __expf(-2.f*x)) - 1.f; }

__device__ __forceinline__ void async_ld16(const ushort* g, ushort* l){
  __builtin_amdgcn_global_load_lds(
      (const __attribute__((address_space(1))) uint32_t*)g,
      (__attribute__((address_space(3))) uint32_t*)l, 16, 0, 0);
}

// ---------------- zero a u32 region ----------------
__global__ void k_zero(uint32_t* p, int n){
  int i = blockIdx.x * 256 + threadIdx.x;
  if (i < n) p[i] = 0;
}

// ---------------- fp32 -> bf16 convert (vectorized x4) ----------------
__global__ void k_convert(const float4* __restrict__ src, ushort4* __restrict__ dst, int n4){
  int i = blockIdx.x * blockDim.x + threadIdx.x;
  if (i < n4){
    float4 v = src[i];
    ushort4 o; o.x = f2bf(v.x); o.y = f2bf(v.y); o.z = f2bf(v.z); o.w = f2bf(v.w);
    dst[i] = o;
  }
}

// ---------------- embedding gather for one chunk -> x_bf16 [CT][B][E] ----------
__global__ void k_gather_c(const int* __restrict__ inp, const float* __restrict__ emb,
                           ushort* __restrict__ xbf, int tbase){
  int row = blockIdx.x;            // i*64 + b
  int s = tbase + (row >> 6), b = row & 63;
  int t = threadIdx.x;
  int v = inp[b * SLEN + s];
  float4 x = ((const float4*)(emb + (size_t)v * EMB))[t];
  ushort4 o; o.x = f2bf(x.x); o.y = f2bf(x.y); o.z = f2bf(x.z); o.w = f2bf(x.w);
  ((ushort4*)(xbf + (size_t)row * EMB))[t] = o;
}

// ---------------- chunk GEMM (m97-style), unchanged ----------------
__global__ __launch_bounds__(256) void k_gemm(const ushort* __restrict__ A,
                                              const ushort* __restrict__ Bw,
                                              const float* __restrict__ bias,
                                              ushort* __restrict__ C, int K,
                                              size_t cDirStride){
  __shared__ __align__(16) ushort sA[128 * 32];
  __shared__ __align__(16) ushort sB[128 * 32];
  const int tid = threadIdx.x;
  const int d = blockIdx.z;
  const size_t mBase = (size_t)blockIdx.x * 128;
  const int nBase = blockIdx.y * 128;
  const ushort* Bd = Bw + (size_t)d * G4 * K;
  const float* biasd = bias + (size_t)d * G4;
  ushort* Cd = C + (size_t)d * cDirStride;
  const int w = tid >> 6, lane = tid & 63;
  const int quad = lane >> 4, c16 = lane & 15;
  const int m0 = (w >> 1) * 64, n0 = (w & 1) * 64;
  const int u0 = tid, u1 = tid + 256;
  const int r0 = u0 >> 2, k0 = (u0 & 3) * 8;
  const int r1 = u1 >> 2, k1 = (u1 & 3) * 8;

  f32x4 acc[4][4] = {};
  for (int kc = 0; kc < K; kc += 32){
    __syncthreads();
    async_ld16(A  + (mBase + r0) * (size_t)K + kc + k0, sA + u0 * 8);
    async_ld16(A  + (mBase + r1) * (size_t)K + kc + k1, sA + u1 * 8);
    async_ld16(Bd + (size_t)(nBase + r0) * K + kc + k0, sB + u0 * 8);
    async_ld16(Bd + (size_t)(nBase + r1) * K + kc + k1, sB + u1 * 8);
    __syncthreads();
    bf16x8 af[4], bfv[4];
#pragma unroll
    for (int mt = 0; mt < 4; ++mt)
      af[mt] = *(const bf16x8*)(sA + (m0 + mt * 16 + c16) * 32 + quad * 8);
#pragma unroll
    for (int nt = 0; nt < 4; ++nt)
      bfv[nt] = *(const bf16x8*)(sB + (n0 + nt * 16 + c16) * 32 + quad * 8);
#pragma unroll
    for (int mt = 0; mt < 4; ++mt)
#pragma unroll
      for (int nt = 0; nt < 4; ++nt)
        acc[mt][nt] = __builtin_amdgcn_mfma_f32_16x16x32_bf16(af[mt], bfv[nt], acc[mt][nt], 0, 0, 0);
  }
#pragma unroll
  for (int nt = 0; nt < 4; ++nt){
    int col = nBase + n0 + nt * 16 + c16;
    float bv = biasd[col];
#pragma unroll
    for (int mt = 0; mt < 4; ++mt){
      size_t rowb = mBase + m0 + mt * 16 + quad * 4;
#pragma unroll
      for (int r = 0; r < 4; ++r)
        Cd[(rowb + r) * G4 + col] = f2bf(acc[mt][nt][r] + bv);
    }
  }
}

// ---------------- combined persistent recurrent kernel: layer0(t) || layer1(t-1) ----
// R3 geometry kept verbatim (blocks 0..255 layer0, 256..511 layer1; per layer:
// block=(d, 16-unit tile jt, batch-half mh), 4 waves = 4 gates). CHANGE vs R3:
// the central 256-wide atomic-counter barrier is replaced by DISTRIBUTED FLAGS
// over dependency-exact groups:
//  * group = (layer,d,mh): block (d,jt,mh) reads h rows [mb,mb+32) of dir d,
//    produced exactly by the 64 blocks (d,*,mh). 8 groups total, independent.
//  * arrival: after h stores drain (vmcnt(0) + __syncthreads), thread 0 stores
//    flags[grp][step][jt] = token  -- plain agent store, NO serialized RMW chain.
//  * release: each wave loads 64 flags with ONE vector load (lane l <-> jt=l)
//    and polls until __all(flag >= token). One LLC round instead of 256 RMWs
//    plus a gen broadcast.
//  * tokens are per-dispatch monotone -> no flag re-zeroing, no ABA; h-data
//    visibility identical to the proven R0/R3 scheme (write-through stores
//    drained before flag store; each h address touched once per dispatch;
//    agent-scope atomic loads observe LLC).
//  * next step's xw words are prefetched under the poll (hides HBM latency).
__global__ __launch_bounds__(256, 2) void k_rec(const ushort* __restrict__ xw0,
                                                const ushort* __restrict__ xw1,
                                                const ushort* __restrict__ whh0,
                                                const ushort* __restrict__ whh1,
                                                const ushort* __restrict__ hinit0,
                                                const ushort* __restrict__ hinit1,
                                                ushort* __restrict__ h0seq,
                                                ushort* __restrict__ h1seq,
                                                float* __restrict__ c0st,
                                                float* __restrict__ c1st,
                                                unsigned* __restrict__ flags,
                                                int act, int tbase0, int tbase1,
                                                unsigned tok0, unsigned tok1,
                                                const int* __restrict__ tgt_idx,
                                                float* __restrict__ tgt_out){
  const int layer = blockIdx.x >> 8;
  if (!((act >> layer) & 1)) return;            // ramp-in/out: half inactive
  const int bx = blockIdx.x & 255;

  const ushort* xw    = layer ? xw1    : xw0;
  const ushort* whh   = layer ? whh1   : whh0;
  const ushort* hinit = layer ? hinit1 : hinit0;
  ushort* hseq        = layer ? h1seq  : h0seq;
  float* cst          = layer ? c1st   : c0st;
  const int mode      = layer;                  // layer1 captures target rows
  const int tbase     = layer ? tbase1 : tbase0;
  const unsigned tok  = layer ? tok1 : tok0;

  const int tid = threadIdx.x;
  const int d  = bx >> 7;                 // direction
  const int jt = (bx & 127) >> 1;         // hidden tile (16 units)
  const int mh = bx & 1;                  // batch half
  const int j0 = jt * 16;
  const int mb = mh * 32;
  const int w = tid >> 6, lane = tid & 63;
  const int quad = lane >> 4, c16 = lane & 15;
  const int g = w;                        // wave's gate (torch order i,f,g,o)
  const int er = tid >> 3;                // epilogue: batch row 0..31
  const int ec = (tid & 7) * 2;           // epilogue: col pair 0,2,..,14

  // flag base for this block's group: [layer][d][mh][CT][64 producers]
  unsigned* fgrp = flags + (size_t)(((layer * 2 + d) * 2 + mh) * CT) * 64;

  __shared__ float sred[4 * 32 * 17];     // [gate][row32][col16+pad]

  // ---- preload this wave's gate weights: 32 frags x 16B = 128 unified regs ----
  bf16x8 bfr[32];
  {
    const ushort* wp = whh + ((size_t)d * G4 + (size_t)g * HID + j0 + c16) * HID + quad * 8;
#pragma unroll
    for (int t = 0; t < 32; ++t) bfr[t] = *(const bf16x8*)(wp + t * 32);
  }

  // ---- cell state: 2 units per thread, registers across the chunk ----
  float cv0 = cst[(size_t)bx * 512 + tid * 2];
  float cv1 = cst[(size_t)bx * 512 + tid * 2 + 1];

  const int tgt_t = mode ? tgt_idx[mb + er] : -1;

  // ---- prefetch xw pre-activations for step 0 ----
  size_t xrow = ((size_t)d * CROWS + (size_t)0 * NBATCH + mb + er) * G4;
  uint32_t xq0 = *(const uint32_t*)(xw + xrow + 0 * HID + j0 + ec);
  uint32_t xq1 = *(const uint32_t*)(xw + xrow + 1 * HID + j0 + ec);
  uint32_t xq2 = *(const uint32_t*)(xw + xrow + 2 * HID + j0 + ec);
  uint32_t xq3 = *(const uint32_t*)(xw + xrow + 3 * HID + j0 + ec);

  for (int i = 0; i < CT; ++i){
    const ushort* hprev = (i == 0) ? hinit : hseq + (size_t)(i - 1) * HSLOT;
    ushort* hout = hseq + (size_t)i * HSLOT;

    // ---- K-loop: h(t-1) x W_hh for this gate, 2 batch tiles of 16 ----
    f32x4 acc0 = {}, acc1 = {};
    const ushort* ap = hprev + (size_t)(mb + c16) * D2H + d * HID + quad * 8;
#pragma unroll
    for (int t = 0; t < 32; ++t){
      bf16x8 a0 = *(const bf16x8*)(ap + t * 32);
      bf16x8 a1 = *(const bf16x8*)(ap + (size_t)16 * D2H + t * 32);
      acc0 = __builtin_amdgcn_mfma_f32_16x16x32_bf16(a0, bfr[t], acc0, 0, 0, 0);
      acc1 = __builtin_amdgcn_mfma_f32_16x16x32_bf16(a1, bfr[t], acc1, 0, 0, 0);
    }

    // ---- stash gate tiles to LDS (D layout: col=c16, row=quad*4+r) ----
#pragma unroll
    for (int r = 0; r < 4; ++r){
      sred[(g * 32 + quad * 4 + r) * 17 + c16]      = acc0[r];
      sred[(g * 32 + 16 + quad * 4 + r) * 17 + c16] = acc1[r];
    }
    __syncthreads();                       // (A) sred writes -> reads

    // ---- per-thread LSTM pointwise for units (er,ec) and (er,ec+1) ----
    float i0 = sred[(0 * 32 + er) * 17 + ec]     + bf2f(xq0 & 0xffffu);
    float i1 = sred[(0 * 32 + er) * 17 + ec + 1] + bf2f(xq0 >> 16);
    float f0 = sred[(1 * 32 + er) * 17 + ec]     + bf2f(xq1 & 0xffffu);
    float f1 = sred[(1 * 32 + er) * 17 + ec + 1] + bf2f(xq1 >> 16);
    float g0 = sred[(2 * 32 + er) * 17 + ec]     + bf2f(xq2 & 0xffffu);
    float g1 = sred[(2 * 32 + er) * 17 + ec + 1] + bf2f(xq2 >> 16);
    float o0 = sred[(3 * 32 + er) * 17 + ec]     + bf2f(xq3 & 0xffffu);
    float o1 = sred[(3 * 32 + er) * 17 + ec + 1] + bf2f(xq3 >> 16);
    float c0 = sigm(f0) * cv0 + sigm(i0) * tanh_s(g0);
    float c1 = sigm(f1) * cv1 + sigm(i1) * tanh_s(g1);
    float h0 = sigm(o0) * tanh_s(c0);
    float h1 = sigm(o1) * tanh_s(c1);
    cv0 = c0; cv1 = c1;

    // write-through packed h (reaches LLC; drained before flag store)
    uint32_t hp = (uint32_t)f2bf(h0) | ((uint32_t)f2bf(h1) << 16);
    size_t hoff = (size_t)(mb + er) * D2H + d * HID + j0 + ec;
    __hip_atomic_store((uint32_t*)(hout + hoff), hp, __ATOMIC_RELAXED, __HIP_MEMORY_SCOPE_AGENT);

    if (mode && tgt_t == tbase + i){
      tgt_out[hoff]     = h0;
      tgt_out[hoff + 1] = h1;
    }

    // ---- distributed flag sync (group fan-in 64, no RMW chain) ----
    if (i != CT - 1){
      __atomic_signal_fence(__ATOMIC_SEQ_CST);
      __builtin_amdgcn_s_waitcnt(0);       // this wave's h stores at LLC
      __syncthreads();                     // (B) all waves drained; sred reads done
      if (tid == 0)
        __hip_atomic_store(fgrp + i * 64 + jt, tok, __ATOMIC_RELAXED, __HIP_MEMORY_SCOPE_AGENT);
      // prefetch next step's xw under the poll (independent of h(t))
      xrow = ((size_t)d * CROWS + (size_t)(i + 1) * NBATCH + mb + er) * G4;
      xq0 = *(const uint32_t*)(xw + xrow + 0 * HID + j0 + ec);
      xq1 = *(const uint32_t*)(xw + xrow + 1 * HID + j0 + ec);
      xq2 = *(const uint32_t*)(xw + xrow + 2 * HID + j0 + ec);
      xq3 = *(const uint32_t*)(xw + xrow + 3 * HID + j0 + ec);
      // poll: lane l waits on producer jt=l of this group (one load / round)
      const unsigned* fq = fgrp + i * 64 + lane;
      while (true){
        unsigned v = __hip_atomic_load(fq, __ATOMIC_RELAXED, __HIP_MEMORY_SCOPE_AGENT);
        if (__all((int)(v >= tok))) break;
        __builtin_amdgcn_s_sleep(1);
      }
      asm volatile("" ::: "memory");       // no hoisting of h loads above the poll
      __atomic_signal_fence(__ATOMIC_SEQ_CST);
    }
  }

  cst[(size_t)bx * 512 + tid * 2]     = cv0;
  cst[(size_t)bx * 512 + tid * 2 + 1] = cv1;
}

// ---------------- final: out[b] = sigmoid(dot(tgt[b], w_cls) + b_cls) ----------------
__global__ __launch_bounds__(256) void k_final(const float* __restrict__ tgt,
                                               const float* __restrict__ wc,
                                               const float* __restrict__ bc,
                                               float* __restrict__ out){
  int b = blockIdx.x, tid = threadIdx.x;
  const float4* tv = (const float4*)(tgt + (size_t)b * D2H);
  const float4* wv = (const float4*)wc;
  float s = 0.f;
  for (int i = tid; i < D2H / 4; i += 256){
    float4 a = tv[i], ww = wv[i];
    s += a.x * ww.x + a.y * ww.y + a.z * ww.z + a.w * ww.w;
  }
  for (int off = 32; off; off >>= 1) s += __shfl_down(s, off, 64);
  __shared__ float red[4];
  if ((tid & 63) == 0) red[tid >> 6] = s;
  __syncthreads();
  if (tid == 0){
    float tot = red[0] + red[1] + red[2] + red[3] + bc[0];
    out[b] = 1.f / (1.f + __expf(-tot));
  }
}

extern "C" void kernel_launch(void* const* d_in, const int* in_sizes, int n_in,
                              void* d_out, int out_size, void* d_ws, size_t ws_size,
                              hipStream_t stream){
  (void)in_sizes; (void)n_in; (void)out_size;
  const int*   inp   = (const int*)  d_in[0];
  const int*   tgtix = (const int*)  d_in[1];
  const float* emb   = (const float*)d_in[2];
  const float* wih0  = (const float*)d_in[3];
  const float* whh0  = (const float*)d_in[4];
  const float* bl0   = (const float*)d_in[5];
  const float* wih1  = (const float*)d_in[6];
  const float* whh1  = (const float*)d_in[7];
  const float* bl1   = (const float*)d_in[8];
  const float* wcls  = (const float*)d_in[9];
  const float* bcls  = (const float*)d_in[10];
  float* out = (float*)d_out;

  // ---- workspace carve ----
  char* p = (char*)d_ws;
  ushort* wih0b = (ushort*)p; p += (size_t)2 * G4 * 1024 * 2;   // 16 MB
  ushort* whh0b = (ushort*)p; p += (size_t)2 * G4 * 1024 * 2;   // 16 MB
  ushort* wih1b = (ushort*)p; p += (size_t)2 * G4 * 2048 * 2;   // 32 MB
  ushort* whh1b = (ushort*)p; p += (size_t)2 * G4 * 1024 * 2;   // 16 MB
  ushort* xbf   = (ushort*)p; p += (size_t)CROWS * EMB * 2;     // 8 MB
  ushort* xw0   = (ushort*)p; p += (size_t)2 * CROWS * G4 * 2;  // 64 MB
  ushort* h0seq = (ushort*)p; p += (size_t)CT * HSLOT * 2;      // 16 MB rolling
  ushort* h1seq = (ushort*)p; p += (size_t)CT * HSLOT * 2;      // 16 MB rolling
  // ---- zeroed region ----
  char* zbase = p;
  ushort* h0zero = (ushort*)p; p += (size_t)HSLOT * 2;            // 256 KB
  float*  c0st   = (float*)p;  p += (size_t)256 * 512 * 4;        // 512 KB
  float*  c1st   = (float*)p;  p += (size_t)256 * 512 * 4;        // 512 KB
  unsigned* flags = (unsigned*)p; p += (size_t)2 * 4 * CT * 64 * 4; // 128 KB
  size_t zbytes = (size_t)(p - zbase);
  // ---- end zero region ----
  float* tgtb = (float*)p; p += (size_t)NBATCH * D2H * 4;       // 512 KB

  // second xw buffer (64 MB) enables the layer-pipelined schedule
  const size_t xwBytes = (size_t)2 * CROWS * G4 * 2;
  bool pipe = ((size_t)(p - (char*)d_ws) + xwBytes) <= ws_size;
  ushort* xw1 = pipe ? (ushort*)p : xw0;

  int zn = (int)(zbytes / 4);
  k_zero<<<dim3((zn + 255) / 256), 256, 0, stream>>>((uint32_t*)zbase, zn);
  k_convert<<<dim3(8192),  256, 0, stream>>>((const float4*)wih0, (ushort4*)wih0b, 2 * G4 * 1024 / 4);
  k_convert<<<dim3(8192),  256, 0, stream>>>((const float4*)whh0, (ushort4*)whh0b, 2 * G4 * 1024 / 4);
  k_convert<<<dim3(16384), 256, 0, stream>>>((const float4*)wih1, (ushort4*)wih1b, 2 * G4 * 2048 / 4);
  k_convert<<<dim3(8192),  256, 0, stream>>>((const float4*)whh1, (ushort4*)whh1b, 2 * G4 * 1024 / 4);

  const size_t cds = (size_t)CROWS * G4;

  if (pipe){
    // software-pipelined: dispatch t runs layer0 chunk t || layer1 chunk t-1
    for (int t = 0; t <= NC; ++t){
      if (t < NC){
        k_gather_c<<<dim3(CROWS), 256, 0, stream>>>(inp, emb, xbf, t * CT);
        k_gemm<<<dim3(CROWS / 128, G4 / 128, 2), 256, 0, stream>>>(xbf, wih0b, bl0, xw0, EMB, cds);
      }
      if (t >= 1)  // reads h0seq written by dispatch t-1's layer0 half
        k_gemm<<<dim3(CROWS / 128, G4 / 128, 2), 256, 0, stream>>>(h0seq, wih1b, bl1, xw1, D2H, cds);
      int act = (t < NC ? 1 : 0) | (t >= 1 ? 2 : 0);
      k_rec<<<dim3(512), 256, 0, stream>>>(xw0, xw1, whh0b, whh1b,
          (t == 0) ? h0zero : h0seq + (size_t)(CT - 1) * HSLOT,
          (t <= 1) ? h0zero : h1seq + (size_t)(CT - 1) * HSLOT,
          h0seq, h1seq, c0st, c1st, flags, act,
          t * CT, (t - 1) * CT,
          (unsigned)(t + 1), (unsigned)t,
          tgtix, tgtb);
    }
  } else {
    // fallback: serial schedule (xw1 == xw0)
    for (int c = 0; c < NC; ++c){
      int tbase = c * CT;
      k_gather_c<<<dim3(CROWS), 256, 0, stream>>>(inp, emb, xbf, tbase);
      k_gemm<<<dim3(CROWS / 128, G4 / 128, 2), 256, 0, stream>>>(xbf, wih0b, bl0, xw0, EMB, cds);
      k_rec<<<dim3(512), 256, 0, stream>>>(xw0, xw1, whh0b, whh1b,
          (c == 0) ? h0zero : h0seq + (size_t)(CT - 1) * HSLOT, h0zero,
          h0seq, h1seq, c0st, c1st, flags, 1,
          tbase, 0, (unsigned)(c + 1), 0u, tgtix, tgtb);
      k_gemm<<<dim3(CROWS / 128, G4 / 128, 2), 256, 0, stream>>>(h0seq, wih1b, bl1, xw1, D2H, cds);
      k_rec<<<dim3(512), 256, 0, stream>>>(xw0, xw1, whh0b, whh1b,
          h0zero, (c == 0) ? h0zero : h1seq + (size_t)(CT - 1) * HSLOT,
          h0seq, h1seq, c0st, c1st, flags, 2,
          0, tbase, 0u, (unsigned)(c + 1), tgtix, tgtb);
    }
  }

  k_final<<<dim3(NBATCH), 256, 0, stream>>>(tgtb, wcls, bcls, out);
}

// Round 5
// 7151.101 us; speedup vs baseline: 1.7436x; 1.7436x over previous
//
#include <hip/hip_runtime.h>
#include <stdint.h>

// Problem constants
#define SLEN 512
#define NBATCH 64
#define EMB 1024
#define HID 1024
#define G4 4096            // 4*H
#define D2H 2048           // 2*H
#define CT 64              // chunk timesteps
#define NC (SLEN/CT)       // 8 chunks
#define CROWS (CT*NBATCH)  // 4096 rows per chunk per dir
#define HSLOT (NBATCH*D2H) // elems per h timestep slot

typedef __bf16 bf16x8 __attribute__((ext_vector_type(8)));
typedef float  f32x4  __attribute__((ext_vector_type(4)));

__device__ __forceinline__ ushort f2bf(float x){
  union { float f; uint32_t u; } v; v.f = x;
  uint32_t r = (v.u + 0x7fffu + ((v.u >> 16) & 1u)) >> 16;   // RNE
  return (ushort)r;
}
__device__ __forceinline__ float bf2f(uint32_t u){
  union { uint32_t u; float f; } v; v.u = u << 16;
  return v.f;
}
__device__ __forceinline__ float sigm(float x){ return 1.f / (1.f + __expf(-x)); }
__device__ __forceinline__ float tanh_s(float x){ return 2.f / (1.f + __expf(-2.f*x)) - 1.f; }

__device__ __forceinline__ void async_ld16(const ushort* g, ushort* l){
  __builtin_amdgcn_global_load_lds(
      (const __attribute__((address_space(1))) uint32_t*)g,
      (__attribute__((address_space(3))) uint32_t*)l, 16, 0, 0);
}

// ---------------- zero a u32 region ----------------
__global__ void k_zero(uint32_t* p, int n){
  int i = blockIdx.x * 256 + threadIdx.x;
  if (i < n) p[i] = 0;
}

// ---------------- fp32 -> bf16 convert (vectorized x4) ----------------
__global__ void k_convert(const float4* __restrict__ src, ushort4* __restrict__ dst, int n4){
  int i = blockIdx.x * blockDim.x + threadIdx.x;
  if (i < n4){
    float4 v = src[i];
    ushort4 o; o.x = f2bf(v.x); o.y = f2bf(v.y); o.z = f2bf(v.z); o.w = f2bf(v.w);
    dst[i] = o;
  }
}

// ---------------- embedding gather for one chunk -> x_bf16 [CT][B][E] ----------
__global__ void k_gather_c(const int* __restrict__ inp, const float* __restrict__ emb,
                           ushort* __restrict__ xbf, int tbase){
  int row = blockIdx.x;            // i*64 + b
  int s = tbase + (row >> 6), b = row & 63;
  int t = threadIdx.x;
  int v = inp[b * SLEN + s];
  float4 x = ((const float4*)(emb + (size_t)v * EMB))[t];
  ushort4 o; o.x = f2bf(x.x); o.y = f2bf(x.y); o.z = f2bf(x.z); o.w = f2bf(x.w);
  ((ushort4*)(xbf + (size_t)row * EMB))[t] = o;
}

// ---------------- chunk GEMM (m97-style), unchanged ----------------
__global__ __launch_bounds__(256) void k_gemm(const ushort* __restrict__ A,
                                              const ushort* __restrict__ Bw,
                                              const float* __restrict__ bias,
                                              ushort* __restrict__ C, int K,
                                              size_t cDirStride){
  __shared__ __align__(16) ushort sA[128 * 32];
  __shared__ __align__(16) ushort sB[128 * 32];
  const int tid = threadIdx.x;
  const int d = blockIdx.z;
  const size_t mBase = (size_t)blockIdx.x * 128;
  const int nBase = blockIdx.y * 128;
  const ushort* Bd = Bw + (size_t)d * G4 * K;
  const float* biasd = bias + (size_t)d * G4;
  ushort* Cd = C + (size_t)d * cDirStride;
  const int w = tid >> 6, lane = tid & 63;
  const int quad = lane >> 4, c16 = lane & 15;
  const int m0 = (w >> 1) * 64, n0 = (w & 1) * 64;
  const int u0 = tid, u1 = tid + 256;
  const int r0 = u0 >> 2, k0 = (u0 & 3) * 8;
  const int r1 = u1 >> 2, k1 = (u1 & 3) * 8;

  f32x4 acc[4][4] = {};
  for (int kc = 0; kc < K; kc += 32){
    __syncthreads();
    async_ld16(A  + (mBase + r0) * (size_t)K + kc + k0, sA + u0 * 8);
    async_ld16(A  + (mBase + r1) * (size_t)K + kc + k1, sA + u1 * 8);
    async_ld16(Bd + (size_t)(nBase + r0) * K + kc + k0, sB + u0 * 8);
    async_ld16(Bd + (size_t)(nBase + r1) * K + kc + k1, sB + u1 * 8);
    __syncthreads();
    bf16x8 af[4], bfv[4];
#pragma unroll
    for (int mt = 0; mt < 4; ++mt)
      af[mt] = *(const bf16x8*)(sA + (m0 + mt * 16 + c16) * 32 + quad * 8);
#pragma unroll
    for (int nt = 0; nt < 4; ++nt)
      bfv[nt] = *(const bf16x8*)(sB + (n0 + nt * 16 + c16) * 32 + quad * 8);
#pragma unroll
    for (int mt = 0; mt < 4; ++mt)
#pragma unroll
      for (int nt = 0; nt < 4; ++nt)
        acc[mt][nt] = __builtin_amdgcn_mfma_f32_16x16x32_bf16(af[mt], bfv[nt], acc[mt][nt], 0, 0, 0);
  }
#pragma unroll
  for (int nt = 0; nt < 4; ++nt){
    int col = nBase + n0 + nt * 16 + c16;
    float bv = biasd[col];
#pragma unroll
    for (int mt = 0; mt < 4; ++mt){
      size_t rowb = mBase + m0 + mt * 16 + quad * 4;
#pragma unroll
      for (int r = 0; r < 4; ++r)
        Cd[(rowb + r) * G4 + col] = f2bf(acc[mt][nt][r] + bv);
    }
  }
}

// ---------------- combined persistent recurrent kernel: layer0(t) || layer1(t-1) ----
// R3/R4 geometry kept (blocks 0..255 layer0, 256..511 layer1; per layer:
// block=(d, 16-unit tile jt, batch-half mh), 4 waves = 4 gates). CHANGE vs R4:
// the h(t-1) panel [32 rows x 1024] is staged into LDS ONCE per block per step
// via global_load_lds (all 4 waves then K-loop from LDS). This removes the 4x
// intra-block LLC read duplication (128 MB -> 32 MB per combined step) that the
// counters identified as the real floor. Source-side XOR swizzle (T2/m173:
// linear LDS dest, pre-swizzled global src, swizzled ds_read) breaks the
// 2048B-row-stride bank aliasing. Poll is gated to wave 0 only (cuts flag-poll
// LLC traffic 4x vs R4).
__global__ __launch_bounds__(256, 2) void k_rec(const ushort* __restrict__ xw0,
                                                const ushort* __restrict__ xw1,
                                                const ushort* __restrict__ whh0,
                                                const ushort* __restrict__ whh1,
                                                const ushort* __restrict__ hinit0,
                                                const ushort* __restrict__ hinit1,
                                                ushort* __restrict__ h0seq,
                                                ushort* __restrict__ h1seq,
                                                float* __restrict__ c0st,
                                                float* __restrict__ c1st,
                                                unsigned* __restrict__ flags,
                                                int act, int tbase0, int tbase1,
                                                unsigned tok0, unsigned tok1,
                                                const int* __restrict__ tgt_idx,
                                                float* __restrict__ tgt_out){
  const int layer = blockIdx.x >> 8;
  if (!((act >> layer) & 1)) return;            // ramp-in/out: half inactive
  const int bx = blockIdx.x & 255;

  const ushort* xw    = layer ? xw1    : xw0;
  const ushort* whh   = layer ? whh1   : whh0;
  const ushort* hinit = layer ? hinit1 : hinit0;
  ushort* hseq        = layer ? h1seq  : h0seq;
  float* cst          = layer ? c1st   : c0st;
  const int mode      = layer;                  // layer1 captures target rows
  const int tbase     = layer ? tbase1 : tbase0;
  const unsigned tok  = layer ? tok1 : tok0;

  const int tid = threadIdx.x;
  const int d  = bx >> 7;                 // direction
  const int jt = (bx & 127) >> 1;         // hidden tile (16 units)
  const int mh = bx & 1;                  // batch half
  const int j0 = jt * 16;
  const int mb = mh * 32;
  const int w = tid >> 6, lane = tid & 63;
  const int quad = lane >> 4, c16 = lane & 15;
  const int g = w;                        // wave's gate (torch order i,f,g,o)
  const int er = tid >> 3;                // epilogue: batch row 0..31
  const int ec = (tid & 7) * 2;           // epilogue: col pair 0,2,..,14

  // flag base for this block's group: [layer][d][mh][CT][64 producers]
  unsigned* fgrp = flags + (size_t)(((layer * 2 + d) * 2 + mh) * CT) * 64;

  __shared__ __align__(16) ushort hS[32 * 1024];  // 64 KB staged h(t-1) panel
  __shared__ float sred[4 * 32 * 17];             // [gate][row32][col16+pad]

  // ---- preload this wave's gate weights: 32 frags x 16B = 128 unified regs ----
  bf16x8 bfr[32];
  {
    const ushort* wp = whh + ((size_t)d * G4 + (size_t)g * HID + j0 + c16) * HID + quad * 8;
#pragma unroll
    for (int t = 0; t < 32; ++t) bfr[t] = *(const bf16x8*)(wp + t * 32);
  }

  // ---- cell state: 2 units per thread, registers across the chunk ----
  float cv0 = cst[(size_t)bx * 512 + tid * 2];
  float cv1 = cst[(size_t)bx * 512 + tid * 2 + 1];

  const int tgt_t = mode ? tgt_idx[mb + er] : -1;

  // staging constants (per thread): linear LDS dest, src column pre-swizzled
  const int stColU = (tid * 8) & 1023;        // column (ushorts) this thread covers
  const int stRB   = tid >> 7;                // row parity bit (tid*8 >> 10)

  // K-loop read swizzle: row = c16 (+16), swizzle key (row&7) is same for both
  const int swz = (c16 & 7) << 3;
  const ushort* bA = hS + c16 * 1024;
  const ushort* bB = hS + (16 + c16) * 1024;

  // ---- stage step-0 panel + prefetch step-0 xw ----
  {
    const ushort* hp = hinit + (size_t)mb * D2H + d * HID;
#pragma unroll
    for (int r = 0; r < 16; ++r){
      int row  = 2 * r + stRB;
      int soff = stColU ^ ((row & 7) << 3);   // involution, matches read XOR
      async_ld16(hp + (size_t)row * D2H + soff, hS + tid * 8 + r * 2048);
    }
  }
  size_t xrow = ((size_t)d * CROWS + mb + er) * G4;
  uint32_t xq0 = *(const uint32_t*)(xw + xrow + 0 * HID + j0 + ec);
  uint32_t xq1 = *(const uint32_t*)(xw + xrow + 1 * HID + j0 + ec);
  uint32_t xq2 = *(const uint32_t*)(xw + xrow + 2 * HID + j0 + ec);
  uint32_t xq3 = *(const uint32_t*)(xw + xrow + 3 * HID + j0 + ec);

  for (int i = 0; i < CT; ++i){
    ushort* hout = hseq + (size_t)i * HSLOT;

    __builtin_amdgcn_s_waitcnt(0);         // (D) staging (and xq) landed
    __syncthreads();

    // ---- K-loop from LDS: h(t-1) x W_hh for this gate, 2 batch tiles of 16 ----
    f32x4 acc0 = {}, acc1 = {};
#pragma unroll
    for (int t = 0; t < 32; ++t){
      int cidx = (t * 32 + quad * 8) ^ swz;
      bf16x8 a0 = *(const bf16x8*)(bA + cidx);
      bf16x8 a1 = *(const bf16x8*)(bB + cidx);
      acc0 = __builtin_amdgcn_mfma_f32_16x16x32_bf16(a0, bfr[t], acc0, 0, 0, 0);
      acc1 = __builtin_amdgcn_mfma_f32_16x16x32_bf16(a1, bfr[t], acc1, 0, 0, 0);
    }

    // ---- stash gate tiles to LDS (D layout: col=c16, row=quad*4+r) ----
#pragma unroll
    for (int r = 0; r < 4; ++r){
      sred[(g * 32 + quad * 4 + r) * 17 + c16]      = acc0[r];
      sred[(g * 32 + 16 + quad * 4 + r) * 17 + c16] = acc1[r];
    }
    __syncthreads();                       // (A) sred writes -> reads

    // ---- per-thread LSTM pointwise for units (er,ec) and (er,ec+1) ----
    float i0 = sred[(0 * 32 + er) * 17 + ec]     + bf2f(xq0 & 0xffffu);
    float i1 = sred[(0 * 32 + er) * 17 + ec + 1] + bf2f(xq0 >> 16);
    float f0 = sred[(1 * 32 + er) * 17 + ec]     + bf2f(xq1 & 0xffffu);
    float f1 = sred[(1 * 32 + er) * 17 + ec + 1] + bf2f(xq1 >> 16);
    float g0 = sred[(2 * 32 + er) * 17 + ec]     + bf2f(xq2 & 0xffffu);
    float g1 = sred[(2 * 32 + er) * 17 + ec + 1] + bf2f(xq2 >> 16);
    float o0 = sred[(3 * 32 + er) * 17 + ec]     + bf2f(xq3 & 0xffffu);
    float o1 = sred[(3 * 32 + er) * 17 + ec + 1] + bf2f(xq3 >> 16);
    float c0 = sigm(f0) * cv0 + sigm(i0) * tanh_s(g0);
    float c1 = sigm(f1) * cv1 + sigm(i1) * tanh_s(g1);
    float h0 = sigm(o0) * tanh_s(c0);
    float h1 = sigm(o1) * tanh_s(c1);
    cv0 = c0; cv1 = c1;

    // write-through packed h (reaches LLC; drained before flag store)
    uint32_t hp2 = (uint32_t)f2bf(h0) | ((uint32_t)f2bf(h1) << 16);
    size_t hoff = (size_t)(mb + er) * D2H + d * HID + j0 + ec;
    __hip_atomic_store((uint32_t*)(hout + hoff), hp2, __ATOMIC_RELAXED, __HIP_MEMORY_SCOPE_AGENT);

    if (mode && tgt_t == tbase + i){
      tgt_out[hoff]     = h0;
      tgt_out[hoff + 1] = h1;
    }

    // ---- distributed flag sync + next-step staging ----
    if (i != CT - 1){
      __atomic_signal_fence(__ATOMIC_SEQ_CST);
      __builtin_amdgcn_s_waitcnt(0);       // this wave's h stores at LLC
      __syncthreads();                     // (B) all waves drained; sred reads done
      if (tid == 0)
        __hip_atomic_store(fgrp + i * 64 + jt, tok, __ATOMIC_RELAXED, __HIP_MEMORY_SCOPE_AGENT);
      if (tid < 64){                       // wave 0 polls for the whole block
        const unsigned* fq = fgrp + i * 64 + lane;
        while (true){
          unsigned v = __hip_atomic_load(fq, __ATOMIC_RELAXED, __HIP_MEMORY_SCOPE_AGENT);
          if (__all((int)(v >= tok))) break;
          __builtin_amdgcn_s_sleep(1);
        }
      }
      __syncthreads();                     // (C) release: panel i is complete
      asm volatile("" ::: "memory");       // no hoisting of panel reads above poll
      // stage next panel (just-written h slot) + prefetch next xw
      {
        const ushort* hp3 = hseq + (size_t)i * HSLOT + (size_t)mb * D2H + d * HID;
#pragma unroll
        for (int r = 0; r < 16; ++r){
          int row  = 2 * r + stRB;
          int soff = stColU ^ ((row & 7) << 3);
          async_ld16(hp3 + (size_t)row * D2H + soff, hS + tid * 8 + r * 2048);
        }
      }
      xrow = ((size_t)d * CROWS + (size_t)(i + 1) * NBATCH + mb + er) * G4;
      xq0 = *(const uint32_t*)(xw + xrow + 0 * HID + j0 + ec);
      xq1 = *(const uint32_t*)(xw + xrow + 1 * HID + j0 + ec);
      xq2 = *(const uint32_t*)(xw + xrow + 2 * HID + j0 + ec);
      xq3 = *(const uint32_t*)(xw + xrow + 3 * HID + j0 + ec);
    }
  }

  cst[(size_t)bx * 512 + tid * 2]     = cv0;
  cst[(size_t)bx * 512 + tid * 2 + 1] = cv1;
}

// ---------------- final: out[b] = sigmoid(dot(tgt[b], w_cls) + b_cls) ----------------
__global__ __launch_bounds__(256) void k_final(const float* __restrict__ tgt,
                                               const float* __restrict__ wc,
                                               const float* __restrict__ bc,
                                               float* __restrict__ out){
  int b = blockIdx.x, tid = threadIdx.x;
  const float4* tv = (const float4*)(tgt + (size_t)b * D2H);
  const float4* wv = (const float4*)wc;
  float s = 0.f;
  for (int i = tid; i < D2H / 4; i += 256){
    float4 a = tv[i], ww = wv[i];
    s += a.x * ww.x + a.y * ww.y + a.z * ww.z + a.w * ww.w;
  }
  for (int off = 32; off; off >>= 1) s += __shfl_down(s, off, 64);
  __shared__ float red[4];
  if ((tid & 63) == 0) red[tid >> 6] = s;
  __syncthreads();
  if (tid == 0){
    float tot = red[0] + red[1] + red[2] + red[3] + bc[0];
    out[b] = 1.f / (1.f + __expf(-tot));
  }
}

extern "C" void kernel_launch(void* const* d_in, const int* in_sizes, int n_in,
                              void* d_out, int out_size, void* d_ws, size_t ws_size,
                              hipStream_t stream){
  (void)in_sizes; (void)n_in; (void)out_size;
  const int*   inp   = (const int*)  d_in[0];
  const int*   tgtix = (const int*)  d_in[1];
  const float* emb   = (const float*)d_in[2];
  const float* wih0  = (const float*)d_in[3];
  const float* whh0  = (const float*)d_in[4];
  const float* bl0   = (const float*)d_in[5];
  const float* wih1  = (const float*)d_in[6];
  const float* whh1  = (const float*)d_in[7];
  const float* bl1   = (const float*)d_in[8];
  const float* wcls  = (const float*)d_in[9];
  const float* bcls  = (const float*)d_in[10];
  float* out = (float*)d_out;

  // ---- workspace carve ----
  char* p = (char*)d_ws;
  ushort* wih0b = (ushort*)p; p += (size_t)2 * G4 * 1024 * 2;   // 16 MB
  ushort* whh0b = (ushort*)p; p += (size_t)2 * G4 * 1024 * 2;   // 16 MB
  ushort* wih1b = (ushort*)p; p += (size_t)2 * G4 * 2048 * 2;   // 32 MB
  ushort* whh1b = (ushort*)p; p += (size_t)2 * G4 * 1024 * 2;   // 16 MB
  ushort* xbf   = (ushort*)p; p += (size_t)CROWS * EMB * 2;     // 8 MB
  ushort* xw0   = (ushort*)p; p += (size_t)2 * CROWS * G4 * 2;  // 64 MB
  ushort* h0seq = (ushort*)p; p += (size_t)CT * HSLOT * 2;      // 16 MB rolling
  ushort* h1seq = (ushort*)p; p += (size_t)CT * HSLOT * 2;      // 16 MB rolling
  // ---- zeroed region ----
  char* zbase = p;
  ushort* h0zero = (ushort*)p; p += (size_t)HSLOT * 2;            // 256 KB
  float*  c0st   = (float*)p;  p += (size_t)256 * 512 * 4;        // 512 KB
  float*  c1st   = (float*)p;  p += (size_t)256 * 512 * 4;        // 512 KB
  unsigned* flags = (unsigned*)p; p += (size_t)2 * 4 * CT * 64 * 4; // 128 KB
  size_t zbytes = (size_t)(p - zbase);
  // ---- end zero region ----
  float* tgtb = (float*)p; p += (size_t)NBATCH * D2H * 4;       // 512 KB

  // second xw buffer (64 MB) enables the layer-pipelined schedule
  const size_t xwBytes = (size_t)2 * CROWS * G4 * 2;
  bool pipe = ((size_t)(p - (char*)d_ws) + xwBytes) <= ws_size;
  ushort* xw1 = pipe ? (ushort*)p : xw0;

  int zn = (int)(zbytes / 4);
  k_zero<<<dim3((zn + 255) / 256), 256, 0, stream>>>((uint32_t*)zbase, zn);
  k_convert<<<dim3(8192),  256, 0, stream>>>((const float4*)wih0, (ushort4*)wih0b, 2 * G4 * 1024 / 4);
  k_convert<<<dim3(8192),  256, 0, stream>>>((const float4*)whh0, (ushort4*)whh0b, 2 * G4 * 1024 / 4);
  k_convert<<<dim3(16384), 256, 0, stream>>>((const float4*)wih1, (ushort4*)wih1b, 2 * G4 * 2048 / 4);
  k_convert<<<dim3(8192),  256, 0, stream>>>((const float4*)whh1, (ushort4*)whh1b, 2 * G4 * 1024 / 4);

  const size_t cds = (size_t)CROWS * G4;

  if (pipe){
    // software-pipelined: dispatch t runs layer0 chunk t || layer1 chunk t-1
    for (int t = 0; t <= NC; ++t){
      if (t < NC){
        k_gather_c<<<dim3(CROWS), 256, 0, stream>>>(inp, emb, xbf, t * CT);
        k_gemm<<<dim3(CROWS / 128, G4 / 128, 2), 256, 0, stream>>>(xbf, wih0b, bl0, xw0, EMB, cds);
      }
      if (t >= 1)  // reads h0seq written by dispatch t-1's layer0 half
        k_gemm<<<dim3(CROWS / 128, G4 / 128, 2), 256, 0, stream>>>(h0seq, wih1b, bl1, xw1, D2H, cds);
      int act = (t < NC ? 1 : 0) | (t >= 1 ? 2 : 0);
      k_rec<<<dim3(512), 256, 0, stream>>>(xw0, xw1, whh0b, whh1b,
          (t == 0) ? h0zero : h0seq + (size_t)(CT - 1) * HSLOT,
          (t <= 1) ? h0zero : h1seq + (size_t)(CT - 1) * HSLOT,
          h0seq, h1seq, c0st, c1st, flags, act,
          t * CT, (t - 1) * CT,
          (unsigned)(t + 1), (unsigned)t,
          tgtix, tgtb);
    }
  } else {
    // fallback: serial schedule (xw1 == xw0)
    for (int c = 0; c < NC; ++c){
      int tbase = c * CT;
      k_gather_c<<<dim3(CROWS), 256, 0, stream>>>(inp, emb, xbf, tbase);
      k_gemm<<<dim3(CROWS / 128, G4 / 128, 2), 256, 0, stream>>>(xbf, wih0b, bl0, xw0, EMB, cds);
      k_rec<<<dim3(512), 256, 0, stream>>>(xw0, xw1, whh0b, whh1b,
          (c == 0) ? h0zero : h0seq + (size_t)(CT - 1) * HSLOT, h0zero,
          h0seq, h1seq, c0st, c1st, flags, 1,
          tbase, 0, (unsigned)(c + 1), 0u, tgtix, tgtb);
      k_gemm<<<dim3(CROWS / 128, G4 / 128, 2), 256, 0, stream>>>(h0seq, wih1b, bl1, xw1, D2H, cds);
      k_rec<<<dim3(512), 256, 0, stream>>>(xw0, xw1, whh0b, whh1b,
          h0zero, (c == 0) ? h0zero : h1seq + (size_t)(CT - 1) * HSLOT,
          h0seq, h1seq, c0st, c1st, flags, 2,
          0, tbase, 0u, (unsigned)(c + 1), tgtix, tgtb);
    }
  }

  k_final<<<dim3(NBATCH), 256, 0, stream>>>(tgtb, wcls, bcls, out);
}